// Round 1
// baseline (354.346 us; speedup 1.0000x reference)
//
#include <hip/hip_runtime.h>

#define D_FEAT 128
#define K_SEG 16

// ---------------------------------------------------------------------------
// Kernel 1: S = softmax(x @ W_seg + b_seg) over K, one thread per node.
// W (128x16 = 8KB) staged in LDS; reads are wave-uniform -> LDS broadcast.
// ---------------------------------------------------------------------------
__global__ void seg_softmax_kernel(const float* __restrict__ x,
                                   const float* __restrict__ W,
                                   const float* __restrict__ b,
                                   float* __restrict__ S_out,
                                   int N)
{
    __shared__ float Ws[D_FEAT * K_SEG];
    __shared__ float bs[K_SEG];
    for (int i = threadIdx.x; i < D_FEAT * K_SEG; i += blockDim.x) Ws[i] = W[i];
    if (threadIdx.x < K_SEG) bs[threadIdx.x] = b[threadIdx.x];
    __syncthreads();

    int node = blockIdx.x * blockDim.x + threadIdx.x;
    if (node >= N) return;

    float acc[K_SEG];
    #pragma unroll
    for (int k = 0; k < K_SEG; k++) acc[k] = bs[k];

    const float4* xr = (const float4*)(x + (size_t)node * D_FEAT);
    #pragma unroll 4
    for (int d4 = 0; d4 < D_FEAT / 4; d4++) {
        float4 v = xr[d4];
        const float* wp = &Ws[d4 * 4 * K_SEG];
        #pragma unroll
        for (int k = 0; k < K_SEG; k++) acc[k] += v.x * wp[k];
        #pragma unroll
        for (int k = 0; k < K_SEG; k++) acc[k] += v.y * wp[K_SEG + k];
        #pragma unroll
        for (int k = 0; k < K_SEG; k++) acc[k] += v.z * wp[2 * K_SEG + k];
        #pragma unroll
        for (int k = 0; k < K_SEG; k++) acc[k] += v.w * wp[3 * K_SEG + k];
    }

    // softmax over K
    float m = acc[0];
    #pragma unroll
    for (int k = 1; k < K_SEG; k++) m = fmaxf(m, acc[k]);
    float sum = 0.f;
    #pragma unroll
    for (int k = 0; k < K_SEG; k++) { acc[k] = __expf(acc[k] - m); sum += acc[k]; }
    float inv = 1.f / sum;

    float* so = S_out + (size_t)node * K_SEG;
    #pragma unroll
    for (int k = 0; k < K_SEG; k++) so[k] = acc[k] * inv;
}

// ---------------------------------------------------------------------------
// Kernel 2: edge pass. 16 lanes per edge (4 edges per wave per iter).
// Lane l (within its 16-lane group): feature chunk [8l, 8l+8) for dist^2,
// then segment k = l for the a/c accumulation.
//   a[k] += w * S[src,k]              (== assoc[k])
//   c[k] += w * S[src,k] * S[tgt,k]   (cut[k] = a[k] - c[k])
// ---------------------------------------------------------------------------
__global__ void edge_kernel(const float* __restrict__ x,
                            const int* __restrict__ ei,
                            const float* __restrict__ S,
                            float* __restrict__ acc_glob, // 32 floats, pre-zeroed
                            int E)
{
    const int lane = threadIdx.x & 63;
    const int sub  = lane >> 4;   // which edge of the quad (0..3)
    const int k    = lane & 15;   // feature-chunk id / segment id
    const int wave_in_block = threadIdx.x >> 6;
    const int gwave  = blockIdx.x * (blockDim.x >> 6) + wave_in_block;
    const int nwaves = gridDim.x * (blockDim.x >> 6);
    const int* __restrict__ src_p = ei;
    const int* __restrict__ tgt_p = ei + E;

    float aa = 0.f, cc = 0.f;

    for (int e4 = gwave * 4; e4 < E; e4 += nwaves * 4) {
        int e = e4 + sub;
        int s = 0, t = 0;
        float dsq = 0.f;
        bool valid = (e < E);
        if (valid) {
            s = src_p[e];  // uniform within 16-lane group -> broadcast
            t = tgt_p[e];
            const float4* xs = (const float4*)(x + (size_t)s * D_FEAT) + k * 2;
            const float4* xt = (const float4*)(x + (size_t)t * D_FEAT) + k * 2;
            float4 a0 = xs[0], a1 = xs[1];
            float4 b0 = xt[0], b1 = xt[1];
            float d;
            d = a0.x - b0.x; dsq += d * d;
            d = a0.y - b0.y; dsq += d * d;
            d = a0.z - b0.z; dsq += d * d;
            d = a0.w - b0.w; dsq += d * d;
            d = a1.x - b1.x; dsq += d * d;
            d = a1.y - b1.y; dsq += d * d;
            d = a1.z - b1.z; dsq += d * d;
            d = a1.w - b1.w; dsq += d * d;
        }
        // reduce dist^2 across the 16-lane group
        dsq += __shfl_xor(dsq, 1, 64);
        dsq += __shfl_xor(dsq, 2, 64);
        dsq += __shfl_xor(dsq, 4, 64);
        dsq += __shfl_xor(dsq, 8, 64);
        float w = __expf(-0.5f * dsq);
        if (valid) {
            float sa = S[(size_t)s * K_SEG + k];
            float st = S[(size_t)t * K_SEG + k];
            float wa = w * sa;
            aa += wa;
            cc += wa * st;
        }
    }

    // fold the 4 sub-groups (same k, different edges)
    aa += __shfl_xor(aa, 16, 64); aa += __shfl_xor(aa, 32, 64);
    cc += __shfl_xor(cc, 16, 64); cc += __shfl_xor(cc, 32, 64);

    __shared__ float red[4][32];
    if (lane < K_SEG) {
        red[wave_in_block][lane]         = aa;
        red[wave_in_block][lane + K_SEG] = cc;
    }
    __syncthreads();
    if (threadIdx.x < 32) {
        float v = red[0][threadIdx.x] + red[1][threadIdx.x]
                + red[2][threadIdx.x] + red[3][threadIdx.x];
        atomicAdd(&acc_glob[threadIdx.x], v);
    }
}

// ---------------------------------------------------------------------------
// Kernel 3: loss = sum_k (a[k] > eps ? (a[k]-c[k])/a[k] : 0)
// ---------------------------------------------------------------------------
__global__ void finalize_kernel(const float* __restrict__ acc_glob,
                                float* __restrict__ out)
{
    if (threadIdx.x == 0) {
        float loss = 0.f;
        for (int kk = 0; kk < K_SEG; kk++) {
            float a = acc_glob[kk];
            float c = acc_glob[kk + K_SEG];
            if (a > 1e-8f) loss += (a - c) / a;
        }
        out[0] = loss;
    }
}

extern "C" void kernel_launch(void* const* d_in, const int* in_sizes, int n_in,
                              void* d_out, int out_size, void* d_ws, size_t ws_size,
                              hipStream_t stream) {
    const float* x  = (const float*)d_in[0];
    const int*   ei = (const int*)d_in[1];
    // d_in[2] = num_expected_segments (scalar, ==16, hardcoded)
    const float* W  = (const float*)d_in[3];
    const float* b  = (const float*)d_in[4];
    float* out = (float*)d_out;

    int N = in_sizes[0] / D_FEAT;
    int E = in_sizes[1] / 2;

    float* S   = out + 1;          // S output doubles as the S buffer
    float* acc = (float*)d_ws;     // 32-float global accumulator

    hipMemsetAsync(acc, 0, 32 * sizeof(float), stream);

    seg_softmax_kernel<<<(N + 255) / 256, 256, 0, stream>>>(x, W, b, S, N);

    edge_kernel<<<2048, 256, 0, stream>>>(x, ei, S, acc, E);

    finalize_kernel<<<1, 64, 0, stream>>>(acc, out);
}

// Round 2
// 263.496 us; speedup vs baseline: 1.3448x; 1.3448x over previous
//
#include <hip/hip_runtime.h>

#define D_FEAT 128
#define K_SEG 16

__device__ __forceinline__ unsigned bf16_rne(float v) {
    unsigned u = __float_as_uint(v);
    return (u + 0x7fffu + ((u >> 16) & 1u)) >> 16;
}

// ---------------------------------------------------------------------------
// Kernel 0: convert x (fp32) -> xb (bf16, RNE). 8 elements per thread.
// ---------------------------------------------------------------------------
__global__ void cvt_bf16_kernel(const float* __restrict__ x,
                                unsigned* __restrict__ xb, // packed 2xbf16 per uint
                                int n8)                    // total elems / 8
{
    int i = blockIdx.x * blockDim.x + threadIdx.x;
    if (i >= n8) return;
    const float4* xin = (const float4*)x;
    float4 a = xin[2 * i], b = xin[2 * i + 1];
    float f[8] = {a.x, a.y, a.z, a.w, b.x, b.y, b.z, b.w};
    uint4 o;
    o.x = bf16_rne(f[0]) | (bf16_rne(f[1]) << 16);
    o.y = bf16_rne(f[2]) | (bf16_rne(f[3]) << 16);
    o.z = bf16_rne(f[4]) | (bf16_rne(f[5]) << 16);
    o.w = bf16_rne(f[6]) | (bf16_rne(f[7]) << 16);
    ((uint4*)xb)[i] = o;
}

// ---------------------------------------------------------------------------
// Kernel 1: S = softmax(x @ W_seg + b_seg). 16 lanes per node.
// Lane k owns features {k, k+16, ..., k+112} -> coalesced 64B loads,
// butterfly-reduce the 16 partial acc vectors, lane k writes S[node,k].
// ---------------------------------------------------------------------------
__global__ void seg_softmax_kernel(const float* __restrict__ x,
                                   const float* __restrict__ W,
                                   const float* __restrict__ b,
                                   float* __restrict__ S_out,
                                   int N)
{
    __shared__ float Ws[D_FEAT * K_SEG];
    __shared__ float bs[K_SEG];
    for (int i = threadIdx.x; i < D_FEAT * K_SEG; i += blockDim.x) Ws[i] = W[i];
    if (threadIdx.x < K_SEG) bs[threadIdx.x] = b[threadIdx.x];
    __syncthreads();

    const int k = threadIdx.x & 15;
    const int node = blockIdx.x * (blockDim.x >> 4) + (threadIdx.x >> 4);
    if (node >= N) return;

    // load my 8 strided features (coalesced across the 16-lane group)
    float xv[8];
    const float* xr = x + (size_t)node * D_FEAT;
    #pragma unroll
    for (int j = 0; j < 8; j++) xv[j] = xr[k + 16 * j];

    float acc[K_SEG];
    #pragma unroll
    for (int s = 0; s < K_SEG; s++) acc[s] = 0.f;
    #pragma unroll
    for (int j = 0; j < 8; j++) {
        const float* wp = &Ws[(k + 16 * j) * K_SEG];
        #pragma unroll
        for (int s = 0; s < K_SEG; s++) acc[s] += xv[j] * wp[s];
    }

    // butterfly-reduce across the 16-lane group: every lane gets full logits
    #pragma unroll
    for (int s = 0; s < K_SEG; s++) {
        acc[s] += __shfl_xor(acc[s], 1, 64);
        acc[s] += __shfl_xor(acc[s], 2, 64);
        acc[s] += __shfl_xor(acc[s], 4, 64);
        acc[s] += __shfl_xor(acc[s], 8, 64);
        acc[s] += bs[s];
    }

    float m = acc[0];
    #pragma unroll
    for (int s = 1; s < K_SEG; s++) m = fmaxf(m, acc[s]);
    float sum = 0.f;
    #pragma unroll
    for (int s = 0; s < K_SEG; s++) { acc[s] = __expf(acc[s] - m); sum += acc[s]; }
    float inv = 1.f / sum;

    // lane k writes element k (coalesced 64B per group)
    float myv = 0.f;
    #pragma unroll
    for (int s = 0; s < K_SEG; s++) if (s == k) myv = acc[s];
    S_out[(size_t)node * K_SEG + k] = myv * inv;
}

// ---------------------------------------------------------------------------
// Kernel 2: edge pass over bf16 x. 16 lanes per edge (4 edges/wave/iter).
// Lane k: bf16 feature chunk [8k, 8k+8) (one 16B load per endpoint) for
// dist^2; then segment k for the a/c accumulation.
//   a[k] += w * S[src,k]              (== assoc[k])
//   c[k] += w * S[src,k] * S[tgt,k]   (cut[k] = a[k] - c[k])
// ---------------------------------------------------------------------------
__global__ void edge_kernel(const float4* __restrict__ xb, // bf16 rows, 16B = 8 feats
                            const int* __restrict__ ei,
                            const float* __restrict__ S,
                            float* __restrict__ acc_glob, // 32 floats, pre-zeroed
                            int E)
{
    const int lane = threadIdx.x & 63;
    const int sub  = lane >> 4;   // which edge of the quad (0..3)
    const int k    = lane & 15;   // feature-chunk id / segment id
    const int wave_in_block = threadIdx.x >> 6;
    const int gwave  = blockIdx.x * (blockDim.x >> 6) + wave_in_block;
    const int nwaves = gridDim.x * (blockDim.x >> 6);
    const int* __restrict__ src_p = ei;
    const int* __restrict__ tgt_p = ei + E;

    float aa = 0.f, cc = 0.f;

    for (int e4 = gwave * 4; e4 < E; e4 += nwaves * 4) {
        int e = e4 + sub;
        int s = 0, t = 0;
        float dsq = 0.f;
        bool valid = (e < E);
        if (valid) {
            s = src_p[e];  // uniform within 16-lane group -> broadcast
            t = tgt_p[e];
            float4 rs = xb[(size_t)s * 16 + k];
            float4 rt = xb[(size_t)t * 16 + k];
            const unsigned* us = (const unsigned*)&rs;
            const unsigned* ut = (const unsigned*)&rt;
            #pragma unroll
            for (int j = 0; j < 4; j++) {
                float slo = __uint_as_float(us[j] << 16);
                float shi = __uint_as_float(us[j] & 0xffff0000u);
                float tlo = __uint_as_float(ut[j] << 16);
                float thi = __uint_as_float(ut[j] & 0xffff0000u);
                float d0 = slo - tlo; dsq += d0 * d0;
                float d1 = shi - thi; dsq += d1 * d1;
            }
        }
        // reduce dist^2 across the 16-lane group
        dsq += __shfl_xor(dsq, 1, 64);
        dsq += __shfl_xor(dsq, 2, 64);
        dsq += __shfl_xor(dsq, 4, 64);
        dsq += __shfl_xor(dsq, 8, 64);
        float w = __expf(-0.5f * dsq);
        if (valid) {
            float sa = S[(size_t)s * K_SEG + k];
            float st = S[(size_t)t * K_SEG + k];
            float wa = w * sa;
            aa += wa;
            cc += wa * st;
        }
    }

    // fold the 4 sub-groups (same k, different edges)
    aa += __shfl_xor(aa, 16, 64); aa += __shfl_xor(aa, 32, 64);
    cc += __shfl_xor(cc, 16, 64); cc += __shfl_xor(cc, 32, 64);

    __shared__ float red[4][32];
    if (lane < K_SEG) {
        red[wave_in_block][lane]         = aa;
        red[wave_in_block][lane + K_SEG] = cc;
    }
    __syncthreads();
    if (threadIdx.x < 32) {
        float v = red[0][threadIdx.x] + red[1][threadIdx.x]
                + red[2][threadIdx.x] + red[3][threadIdx.x];
        atomicAdd(&acc_glob[threadIdx.x], v);
    }
}

// ---------------------------------------------------------------------------
// Kernel 3: loss = sum_k (a[k] > eps ? (a[k]-c[k])/a[k] : 0)
// ---------------------------------------------------------------------------
__global__ void finalize_kernel(const float* __restrict__ acc_glob,
                                float* __restrict__ out)
{
    if (threadIdx.x == 0) {
        float loss = 0.f;
        for (int kk = 0; kk < K_SEG; kk++) {
            float a = acc_glob[kk];
            float c = acc_glob[kk + K_SEG];
            if (a > 1e-8f) loss += (a - c) / a;
        }
        out[0] = loss;
    }
}

extern "C" void kernel_launch(void* const* d_in, const int* in_sizes, int n_in,
                              void* d_out, int out_size, void* d_ws, size_t ws_size,
                              hipStream_t stream) {
    const float* x  = (const float*)d_in[0];
    const int*   ei = (const int*)d_in[1];
    // d_in[2] = num_expected_segments (scalar, ==16, hardcoded)
    const float* W  = (const float*)d_in[3];
    const float* b  = (const float*)d_in[4];
    float* out = (float*)d_out;

    int N = in_sizes[0] / D_FEAT;
    int E = in_sizes[1] / 2;

    float* S   = out + 1;          // S output doubles as the S buffer
    float* acc = (float*)d_ws;     // 32-float global accumulator
    unsigned* xb = (unsigned*)((char*)d_ws + 256); // bf16 copy of x (N*D*2 bytes)

    hipMemsetAsync(acc, 0, 32 * sizeof(float), stream);

    int n8 = N * D_FEAT / 8;
    cvt_bf16_kernel<<<(n8 + 255) / 256, 256, 0, stream>>>(x, xb, n8);

    seg_softmax_kernel<<<(N + 15) / 16, 256, 0, stream>>>(x, W, b, S, N);

    edge_kernel<<<2048, 256, 0, stream>>>((const float4*)xb, ei, S, acc, E);

    finalize_kernel<<<1, 64, 0, stream>>>(acc, out);
}

// Round 3
// 172.392 us; speedup vs baseline: 2.0555x; 1.5285x over previous
//
#include <hip/hip_runtime.h>

#define D_FEAT 128
#define K_SEG 16

typedef float f32x2 __attribute__((ext_vector_type(2)));

__device__ __forceinline__ unsigned short bf16_rne(float v) {
    unsigned u = __float_as_uint(v);
    return (unsigned short)((u + 0x7fffu + ((u >> 16) & 1u)) >> 16);
}
__device__ __forceinline__ unsigned char fp8_enc(float v) {
    return (unsigned char)(__builtin_amdgcn_cvt_pk_fp8_f32(v, v, 0, false) & 0xff);
}

// ---------------------------------------------------------------------------
// Kernel 1 (fused node pass): 16 lanes per node.
//   - lane k owns features {k, k+16, ..., k+112} (coalesced fp32 loads)
//   - logits via LDS W^T (conflict-free: banks (k+16j)%32 distinct per group)
//   - butterfly-reduce, softmax
//   - writes: S fp32 (output), S bf16 (edge-pass copy), x fp8 (edge-pass copy)
// ---------------------------------------------------------------------------
__global__ void node_pass_kernel(const float* __restrict__ x,
                                 const float* __restrict__ W,   // (D,K) row-major
                                 const float* __restrict__ b,
                                 float* __restrict__ S_out,
                                 unsigned char* __restrict__ xq,
                                 unsigned short* __restrict__ Sb,
                                 int N)
{
    __shared__ float Wt[K_SEG * D_FEAT];  // Wt[s*128 + d] = W[d*16 + s]
    __shared__ float bs[K_SEG];
    for (int i = threadIdx.x; i < D_FEAT * K_SEG; i += blockDim.x)
        Wt[(i & 15) * D_FEAT + (i >> 4)] = W[i];
    if (threadIdx.x < K_SEG) bs[threadIdx.x] = b[threadIdx.x];
    __syncthreads();

    const int k = threadIdx.x & 15;
    const int node = blockIdx.x * (blockDim.x >> 4) + (threadIdx.x >> 4);
    if (node >= N) return;

    float xv[8];
    const float* xr = x + (size_t)node * D_FEAT;
    #pragma unroll
    for (int j = 0; j < 8; j++) xv[j] = xr[k + 16 * j];

    float acc[K_SEG];
    #pragma unroll
    for (int s = 0; s < K_SEG; s++) acc[s] = 0.f;
    #pragma unroll
    for (int j = 0; j < 8; j++) {
        const float v = xv[j];
        const float* wp = &Wt[k + 16 * j];
        #pragma unroll
        for (int s = 0; s < K_SEG; s++) acc[s] += v * wp[s * D_FEAT];
    }

    #pragma unroll
    for (int s = 0; s < K_SEG; s++) {
        acc[s] += __shfl_xor(acc[s], 1, 64);
        acc[s] += __shfl_xor(acc[s], 2, 64);
        acc[s] += __shfl_xor(acc[s], 4, 64);
        acc[s] += __shfl_xor(acc[s], 8, 64);
        acc[s] += bs[s];
    }

    float m = acc[0];
    #pragma unroll
    for (int s = 1; s < K_SEG; s++) m = fmaxf(m, acc[s]);
    float sum = 0.f;
    #pragma unroll
    for (int s = 0; s < K_SEG; s++) { acc[s] = __expf(acc[s] - m); sum += acc[s]; }
    float inv = 1.f / sum;

    float myv = 0.f;
    #pragma unroll
    for (int s = 0; s < K_SEG; s++) myv = (s == k) ? acc[s] : myv;
    float p = myv * inv;

    S_out[(size_t)node * K_SEG + k] = p;          // exact fp32 output
    Sb[(size_t)node * K_SEG + k] = bf16_rne(p);   // edge-pass copy

    unsigned char* xrow = xq + (size_t)node * D_FEAT;
    #pragma unroll
    for (int j = 0; j < 8; j++) xrow[k + 16 * j] = fp8_enc(xv[j]);
}

// ---------------------------------------------------------------------------
// Kernel 2: edge pass over fp8 x + bf16 S. 8 lanes per edge (8 edges/wave/iter).
// Lane j: fp8 chunk [16j, 16j+16) (one uint4 per endpoint), segments {2j,2j+1}.
//   a[k] += w * S[src,k]              (== assoc[k])
//   c[k] += w * S[src,k] * S[tgt,k]   (cut[k] = a[k] - c[k])
// ---------------------------------------------------------------------------
__global__ void edge_kernel(const uint4* __restrict__ xq,       // 8 uint4 per node
                            const int* __restrict__ ei,
                            const unsigned* __restrict__ Sb,    // 8 uints per node
                            float* __restrict__ acc_glob,       // 32 floats, zeroed
                            int E)
{
    const int lane = threadIdx.x & 63;
    const int sub  = lane >> 3;   // which edge of the oct (0..7)
    const int j    = lane & 7;    // chunk id / segment-pair id
    const int wave_in_block = threadIdx.x >> 6;
    const int gwave  = blockIdx.x * (blockDim.x >> 6) + wave_in_block;
    const int nwaves = gridDim.x * (blockDim.x >> 6);
    const int* __restrict__ src_p = ei;
    const int* __restrict__ tgt_p = ei + E;

    float a0 = 0.f, a1 = 0.f, c0 = 0.f, c1 = 0.f;

    for (int e8 = gwave * 8; e8 < E; e8 += nwaves * 8) {
        const int e = e8 + sub;              // uniform within the 8-lane group
        const bool valid = (e < E);
        int s = 0, t = 0;
        float dsq = 0.f;
        if (valid) {
            s = src_p[e];
            t = tgt_p[e];
            uint4 ra = xq[(size_t)s * 8 + j];
            uint4 rb = xq[(size_t)t * 8 + j];
            const unsigned* ua = (const unsigned*)&ra;
            const unsigned* ub = (const unsigned*)&rb;
            #pragma unroll
            for (int q = 0; q < 4; q++) {
                f32x2 slo = __builtin_amdgcn_cvt_pk_f32_fp8((int)ua[q], false);
                f32x2 shi = __builtin_amdgcn_cvt_pk_f32_fp8((int)ua[q], true);
                f32x2 tlo = __builtin_amdgcn_cvt_pk_f32_fp8((int)ub[q], false);
                f32x2 thi = __builtin_amdgcn_cvt_pk_f32_fp8((int)ub[q], true);
                float d;
                d = slo.x - tlo.x; dsq = fmaf(d, d, dsq);
                d = slo.y - tlo.y; dsq = fmaf(d, d, dsq);
                d = shi.x - thi.x; dsq = fmaf(d, d, dsq);
                d = shi.y - thi.y; dsq = fmaf(d, d, dsq);
            }
        }
        // reduce dist^2 across the 8-lane group
        dsq += __shfl_xor(dsq, 1, 64);
        dsq += __shfl_xor(dsq, 2, 64);
        dsq += __shfl_xor(dsq, 4, 64);
        float w = __expf(-0.5f * dsq);
        if (valid) {
            unsigned us = Sb[(size_t)s * 8 + j];   // segs 2j (lo), 2j+1 (hi), bf16
            unsigned ut = Sb[(size_t)t * 8 + j];
            float ss0 = __uint_as_float(us << 16);
            float ss1 = __uint_as_float(us & 0xffff0000u);
            float st0 = __uint_as_float(ut << 16);
            float st1 = __uint_as_float(ut & 0xffff0000u);
            float wa0 = w * ss0, wa1 = w * ss1;
            a0 += wa0; c0 += wa0 * st0;
            a1 += wa1; c1 += wa1 * st1;
        }
    }

    // fold the 8 sub-groups (same j, different edges)
    #pragma unroll
    for (int d = 8; d < 64; d <<= 1) {
        a0 += __shfl_xor(a0, d, 64);
        a1 += __shfl_xor(a1, d, 64);
        c0 += __shfl_xor(c0, d, 64);
        c1 += __shfl_xor(c1, d, 64);
    }

    __shared__ float red[4][32];
    if (lane < 8) {
        red[wave_in_block][2 * j]          = a0;
        red[wave_in_block][2 * j + 1]      = a1;
        red[wave_in_block][16 + 2 * j]     = c0;
        red[wave_in_block][16 + 2 * j + 1] = c1;
    }
    __syncthreads();
    if (threadIdx.x < 32) {
        float v = red[0][threadIdx.x] + red[1][threadIdx.x]
                + red[2][threadIdx.x] + red[3][threadIdx.x];
        atomicAdd(&acc_glob[threadIdx.x], v);
    }
}

// ---------------------------------------------------------------------------
// Kernel 3: loss = sum_k (a[k] > eps ? (a[k]-c[k])/a[k] : 0)
// ---------------------------------------------------------------------------
__global__ void finalize_kernel(const float* __restrict__ acc_glob,
                                float* __restrict__ out)
{
    if (threadIdx.x == 0) {
        float loss = 0.f;
        for (int kk = 0; kk < K_SEG; kk++) {
            float a = acc_glob[kk];
            float c = acc_glob[kk + K_SEG];
            if (a > 1e-8f) loss += (a - c) / a;
        }
        out[0] = loss;
    }
}

extern "C" void kernel_launch(void* const* d_in, const int* in_sizes, int n_in,
                              void* d_out, int out_size, void* d_ws, size_t ws_size,
                              hipStream_t stream) {
    const float* x  = (const float*)d_in[0];
    const int*   ei = (const int*)d_in[1];
    // d_in[2] = num_expected_segments (scalar, ==16, hardcoded)
    const float* W  = (const float*)d_in[3];
    const float* b  = (const float*)d_in[4];
    float* out = (float*)d_out;

    int N = in_sizes[0] / D_FEAT;
    int E = in_sizes[1] / 2;

    float* S = out + 1;                       // S output doubles as the S buffer
    float* acc = (float*)d_ws;                // 32-float accumulator
    unsigned char* xq = (unsigned char*)d_ws + 256;          // fp8 x (N*128 B)
    unsigned short* Sb = (unsigned short*)(xq + (size_t)N * D_FEAT); // bf16 S

    hipMemsetAsync(acc, 0, 32 * sizeof(float), stream);

    node_pass_kernel<<<(N + 15) / 16, 256, 0, stream>>>(x, W, b, S, xq, Sb, N);

    edge_kernel<<<2048, 256, 0, stream>>>((const uint4*)xq, ei,
                                          (const unsigned*)Sb, acc, E);

    finalize_kernel<<<1, 64, 0, stream>>>(acc, out);
}